// Round 22
// baseline (182.661 us; speedup 1.0000x reference)
//
#include <hip/hip_runtime.h>

#define S_LEN 4096
#define NH 12
#define HD 64
#define DMODEL 768
#define BATCH 2
#define MTOT (BATCH * S_LEN) /* 8192 */

typedef __bf16 bf16x8 __attribute__((ext_vector_type(8)));
typedef __bf16 bf16x4 __attribute__((ext_vector_type(4)));
typedef float f32x4 __attribute__((ext_vector_type(4)));
typedef float f32x8 __attribute__((ext_vector_type(8)));

#define SM_SCALE_LOG2E 0.18033688f /* 0.125 * log2(e), folded into Q at GEMM1 */
#define SLAB_STRIDE 33792          /* 256x64 bf16 O (32768) + 256 f32 rowsum (1024) */

__device__ __forceinline__ f32x4 f32x4_zero() {
  f32x4 z = {0.f, 0.f, 0.f, 0.f};
  return z;
}

// async global->LDS DMA, 16B per lane. LDS dest = wave-uniform base + lane*16
// (linear); swizzled layouts realized by pre-swizzling the per-lane GLOBAL
// source address (rule #21). Drained by the vmcnt(0) before s_barrier.
__device__ __forceinline__ void async16(const __bf16* g, void* l) {
  __builtin_amdgcn_global_load_lds(
      (const __attribute__((address_space(1))) void*)g,
      (__attribute__((address_space(3))) void*)l, 16, 0, 0);
}

// ---------------- merged prep: cvt x->bf16 + transpose both weights ----------------
__global__ __launch_bounds__(256) void prep_all(const float* __restrict__ x,
                                                const float* __restrict__ Wqkv,
                                                const float* __restrict__ Wout,
                                                __bf16* __restrict__ xb,
                                                __bf16* __restrict__ Wqkv_t,
                                                __bf16* __restrict__ Wout_t) {
  __shared__ __bf16 t[64][72];  // padded (transpose path only)
  const int bid = blockIdx.x;
  if (bid < 3072) {
    int i = bid * 256 + threadIdx.x;
    f32x8 a = ((const f32x8*)x)[i];
    bf16x8 o;
#pragma unroll
    for (int j = 0; j < 8; ++j) o[j] = (__bf16)a[j];
    ((bf16x8*)xb)[i] = o;
    return;
  }
  const float* in;
  __bf16* out;
  int N, v;
  if (bid < 3504) {
    in = Wqkv;
    out = Wqkv_t;
    N = 3 * DMODEL;
    v = bid - 3072;  // 0..431 = 12 kb x 36 nb
  } else {
    in = Wout;
    out = Wout_t;
    N = DMODEL;
    v = bid - 3504;  // 0..143 = 12 kb x 12 nb
  }
  int kb = (v % 12) * 64, nb = (v / 12) * 64;
  int c = threadIdx.x & 63, r0 = threadIdx.x >> 6;
#pragma unroll
  for (int i = 0; i < 16; ++i) {
    int r = r0 * 16 + i;
    t[c][r] = (__bf16)in[(size_t)(kb + r) * N + nb + c];
  }
  __syncthreads();
#pragma unroll
  for (int i = 0; i < 16; ++i) {
    int r = r0 * 16 + i;
    out[(size_t)(nb + r) * DMODEL + kb + c] = t[r][c];
  }
}

// ---------------- shared GEMM core: C[128x128] += A[128xK] * Bt[128xK]^T ----------------
__device__ __forceinline__ void gemm128_bt(const __bf16* __restrict__ A,
                                           const __bf16* __restrict__ Bt,
                                           int m0, int n0, int K,
                                           __bf16* Alds, __bf16* Blds,
                                           f32x4 acc[4][4]) {
  const int tid = threadIdx.x;
  const int l = tid & 63, w = tid >> 6;
  const int wr = w >> 1, wc = w & 1;
  const int g = l >> 4, ln = l & 15;

  const int rr = tid >> 3;
  const int sx = (tid & 7) ^ (rr & 7);
  const __bf16* As = A + (size_t)(m0 + rr) * K + sx * 8;
  const __bf16* Bs = Bt + (size_t)(n0 + rr) * K + sx * 8;
  char* Ad = (char*)Alds + (w << 10);
  char* Bd = (char*)Blds + (w << 10);

  for (int k0 = 0; k0 < K; k0 += 64) {
#pragma unroll
    for (int i = 0; i < 4; ++i) {
      async16(As + (size_t)(i * 32) * K + k0, Ad + i * 4096);
      async16(Bs + (size_t)(i * 32) * K + k0, Bd + i * 4096);
    }
    __syncthreads();
#pragma unroll
    for (int kk = 0; kk < 2; ++kk) {
      bf16x8 af[4], bfr[4];
#pragma unroll
      for (int mi = 0; mi < 4; ++mi) {
        int row = wr * 64 + mi * 16 + ln;
        af[mi] = *(const bf16x8*)(Alds + row * 64 + ((((kk << 2) + g) ^ (row & 7)) << 3));
      }
#pragma unroll
      for (int ni = 0; ni < 4; ++ni) {
        int row = wc * 64 + ni * 16 + ln;
        bfr[ni] = *(const bf16x8*)(Blds + row * 64 + ((((kk << 2) + g) ^ (row & 7)) << 3));
      }
#pragma unroll
      for (int mi = 0; mi < 4; ++mi)
#pragma unroll
        for (int ni = 0; ni < 4; ++ni)
          acc[mi][ni] =
              __builtin_amdgcn_mfma_f32_16x16x32_bf16(af[mi], bfr[ni], acc[mi][ni], 0, 0, 0);
    }
    __syncthreads();
  }
}

// ---------------- GEMM1: qkv = xb @ Wqkv + bqkv; Q pre-scaled by 0.125*log2e;
// scatter Q,K [B,H,S,Hd]; V transposed [B,H,Hd,S] ----------------
__global__ __launch_bounds__(256) void gemm_qkv(const __bf16* __restrict__ xb,
                                                const __bf16* __restrict__ Wt,
                                                const float* __restrict__ bqkv,
                                                __bf16* __restrict__ Qo,
                                                __bf16* __restrict__ Ko,
                                                __bf16* __restrict__ Vto) {
  __shared__ __bf16 Alds[128 * 64];
  __shared__ __bf16 Blds[128 * 64];
  int bm = blockIdx.x & 63, bn = blockIdx.x >> 6;
  int m0 = bm * 128, n0 = bn * 128;
  f32x4 acc[4][4];
#pragma unroll
  for (int i = 0; i < 4; ++i)
#pragma unroll
    for (int j = 0; j < 4; ++j) acc[i][j] = f32x4_zero();
  gemm128_bt(xb, Wt, m0, n0, DMODEL, Alds, Blds, acc);

  const int l = threadIdx.x & 63, w = threadIdx.x >> 6;
  const int wr = w >> 1, wc = w & 1, g = l >> 4, ln = l & 15;
#pragma unroll
  for (int ni = 0; ni < 4; ++ni) {
    int ncol = n0 + wc * 64 + ni * 16 + ln;
    int which = ncol / DMODEL;  // 0=q 1=k 2=v (uniform per 16-col fragment)
    int dd = ncol - which * DMODEL;
    int h = dd >> 6, hd = dd & 63;
    float bias = bqkv[ncol];
    if (which == 2) {
#pragma unroll
      for (int mi = 0; mi < 4; ++mi)
#pragma unroll
        for (int r = 0; r < 4; ++r) {
          int mrow = m0 + wr * 64 + mi * 16 + 4 * g + r;
          int b = mrow >> 12, s = mrow & (S_LEN - 1);
          float v = acc[mi][ni][r] + bias;
          Vto[(((size_t)(b * NH + h) * HD) + hd) * S_LEN + s] = (__bf16)v;
        }
    } else {
      __bf16* op = (which == 0) ? Qo : Ko;
      const float scl = (which == 0) ? SM_SCALE_LOG2E : 1.0f;
#pragma unroll
      for (int mi = 0; mi < 4; ++mi)
#pragma unroll
        for (int r = 0; r < 4; ++r) {
          int mrow = m0 + wr * 64 + mi * 16 + 4 * g + r;
          int b = mrow >> 12, s = mrow & (S_LEN - 1);
          float v = (acc[mi][ni][r] + bias) * scl;
          op[((((size_t)b * NH + h) * S_LEN) + s) * HD + hd] = (__bf16)v;
        }
    }
  }
}

// ---------------- GEMM2: out = Yb @ Wout + bout (fp32 out) ----------------
__global__ __launch_bounds__(256) void gemm_out(const __bf16* __restrict__ yb,
                                                const __bf16* __restrict__ Wt,
                                                const float* __restrict__ bout,
                                                float* __restrict__ out) {
  __shared__ __bf16 Alds[128 * 64];
  __shared__ __bf16 Blds[128 * 64];
  int bm = blockIdx.x & 63, bn = blockIdx.x >> 6;
  int m0 = bm * 128, n0 = bn * 128;
  f32x4 acc[4][4];
#pragma unroll
  for (int i = 0; i < 4; ++i)
#pragma unroll
    for (int j = 0; j < 4; ++j) acc[i][j] = f32x4_zero();
  gemm128_bt(yb, Wt, m0, n0, DMODEL, Alds, Blds, acc);

  const int l = threadIdx.x & 63, w = threadIdx.x >> 6;
  const int wr = w >> 1, wc = w & 1, g = l >> 4, ln = l & 15;
#pragma unroll
  for (int ni = 0; ni < 4; ++ni) {
    int ncol = n0 + wc * 64 + ni * 16 + ln;
    float bias = bout[ncol];
#pragma unroll
    for (int mi = 0; mi < 4; ++mi)
#pragma unroll
      for (int r = 0; r < 4; ++r) {
        int mrow = m0 + wr * 64 + mi * 16 + 4 * g + r;
        out[(size_t)mrow * DMODEL + ncol] = acc[mi][ni][r] + bias;
      }
  }
}

// ---------------- causal flash attention v22: v18 body, 16-wave blocks ----------------
// Same single-barrier iteration and per-wave math as v18 (session best). The
// 32KB K/V double-buffer now serves 16 waves (1024 threads): LDS = 32 KV +
// 16x2 P = 64KB -> 2 blocks/CU x 16 waves = 32 waves/CU (100% ceiling; v18:
// 24). Staging: threads <512 stage K, >=512 stage V (one async16 each).
// Chunk = 256 q-rows; T = 4c+4 tiles; np = ceil(T/16) parts -> 960 units all
// <=16 iters, heavy-first, XCD head affinity; exact partial slabs + combine.
__global__ __launch_bounds__(1024) void attn_fwd22(const __bf16* __restrict__ Q,
                                                   const __bf16* __restrict__ K,
                                                   const __bf16* __restrict__ Vt,
                                                   __bf16* __restrict__ Y,
                                                   char* __restrict__ Po) {
  __shared__ __bf16 KVl[2][2][4096];  // [buf][K/V][8KB]: K [64kv][64d], V [64d][64kv]
  __shared__ char Plb[16][2048];      // per-wave P bounce [16 q][64 kv] pitch 128 + XOR

  const int tid = threadIdx.x;
  const int wv = tid >> 6, l = tid & 63;
  const int g = l >> 4, ln = l & 15;
  const int bi = blockIdx.x;
  const int xcd = bi & 7, j = bi >> 3;  // j in 0..119
  const int head = xcd * 3 + (j % 3);   // 3 heads per XCD
  const int r_ = j / 3;                 // rank 0..39, heavy-first

  // rank -> (chunk c of 256 rows, part, np); T = 4c+4 kv-tiles
  int c, part, np;
  bool split;
  if (r_ < 16) {  // c=15..12, np=4
    c = 15 - (r_ >> 2);
    part = r_ & 3;
    np = 4;
    split = true;
  } else if (r_ < 28) {  // c=11..8, np=3
    int q = r_ - 16;
    c = 11 - q / 3;
    part = q % 3;
    np = 3;
    split = true;
  } else if (r_ < 36) {  // c=7..4, np=2
    int q = r_ - 28;
    c = 7 - (q >> 1);
    part = q & 1;
    np = 2;
    split = true;
  } else {  // c=3..0, direct
    c = 39 - r_;
    part = 0;
    np = 1;
    split = false;
  }
  const int T = 4 * c + 4;
  const int base = T / np, rem = T % np;
  const int t0 = part * base + (part < rem ? part : rem);
  const int t1 = t0 + base + (part < rem ? 1 : 0);

  const int q0 = 256 * c + 16 * wv;  // wave's first q row (global)

  const size_t hb = (size_t)head * (S_LEN * HD);
  const __bf16* Qh = Q + hb;
  const __bf16* Kh = K + hb;
  const __bf16* Vh = Vt + hb;  // [HD][S]

  const int sw = (ln & 7) << 4;
  char* Pw = Plb[wv] + ln * 128;

  // staging: threads <512 stage K, >=512 stage V; each covers one 16B granule.
  const int st = tid & 511;
  const int rr = st >> 3;
  const int ss = (st & 7) ^ (rr & 7);
  const bool isK = tid < 512;
  const size_t gL = isK ? ((size_t)rr * HD + ss * 8) : ((size_t)rr * S_LEN + ss * 8);
  const int ldso = (wv & 7) << 10;  // wave-uniform dest base within 8KB tile

  bf16x8 qf[2];
#pragma unroll
  for (int t = 0; t < 2; ++t)
    qf[t] = *(const bf16x8*)(Qh + (size_t)(q0 + ln) * HD + 32 * t + 8 * g);

  bf16x8 ones;
#pragma unroll
  for (int t = 0; t < 8; ++t) ones[t] = (__bf16)1.0f;

  f32x4 o[4], o5;
#pragma unroll
  for (int nt = 0; nt < 4; ++nt) o[nt] = f32x4_zero();
  o5 = f32x4_zero();

  // prologue: stage tile t0 into buf 0
  const __bf16* kq = Kh + (size_t)t0 * 64 * HD;
  const __bf16* vq = Vh + t0 * 64;
  {
    if (isK) async16(kq + gL, (char*)&KVl[0][0][0] + ldso);
    else async16(vq + gL, (char*)&KVl[0][1][0] + ldso);
    __syncthreads();
  }
  kq += (size_t)64 * HD;
  vq += 64;

  int cur = 0;
  for (int i = t0; i < t1; ++i) {
    const bool more = (i + 1) < t1;
    if (more) {  // DMA next tile into buf^1 (drained by end-of-iter barrier)
      if (isK) async16(kq + gL, (char*)&KVl[cur ^ 1][0][0] + ldso);
      else async16(vq + gL, (char*)&KVl[cur ^ 1][1][0] + ldso);
      kq += (size_t)64 * HD;
      vq += 64;
    }

    const __bf16* Kl = &KVl[cur][0][0];
    const __bf16* Vl = &KVl[cur][1][0];
    const int rel = q0 - 64 * i;  // >=63 full; <=-16 fully masked; else partial

    if (rel > -16) {
      // ---- QK^T + fused softmax -> P bounce ----
      if (rel >= 63) {
#pragma unroll
        for (int jt = 0; jt < 4; ++jt) {
          int row = 16 * jt + ln;
          bf16x8 kf0 = *(const bf16x8*)(Kl + row * 64 + ((g ^ (row & 7)) << 3));
          bf16x8 kf1 = *(const bf16x8*)(Kl + row * 64 + (((4 + g) ^ (row & 7)) << 3));
          f32x4 z = f32x4_zero();
          z = __builtin_amdgcn_mfma_f32_16x16x32_bf16(kf0, qf[0], z, 0, 0, 0);
          z = __builtin_amdgcn_mfma_f32_16x16x32_bf16(kf1, qf[1], z, 0, 0, 0);
          bf16x4 qd;
#pragma unroll
          for (int r = 0; r < 4; ++r) qd[r] = (__bf16)__builtin_exp2f(z[r]);
          *(bf16x4*)(Pw + ((32 * jt + 8 * g) ^ sw)) = qd;
        }
      } else {
        const int thr = rel + ln;
#pragma unroll
        for (int jt = 0; jt < 4; ++jt) {
          int row = 16 * jt + ln;
          bf16x8 kf0 = *(const bf16x8*)(Kl + row * 64 + ((g ^ (row & 7)) << 3));
          bf16x8 kf1 = *(const bf16x8*)(Kl + row * 64 + (((4 + g) ^ (row & 7)) << 3));
          f32x4 z = f32x4_zero();
          z = __builtin_amdgcn_mfma_f32_16x16x32_bf16(kf0, qf[0], z, 0, 0, 0);
          z = __builtin_amdgcn_mfma_f32_16x16x32_bf16(kf1, qf[1], z, 0, 0, 0);
          bf16x4 qd;
#pragma unroll
          for (int r = 0; r < 4; ++r) {
            float pv = __builtin_exp2f(z[r]);
            if (16 * jt + 4 * g + r > thr) pv = 0.f;
            qd[r] = (__bf16)pv;
          }
          *(bf16x4*)(Pw + ((32 * jt + 8 * g) ^ sw)) = qd;
        }
      }

      // ---- PV + ones row-sum ----
      bf16x8 pa0 = *(const bf16x8*)(Pw + ((16 * g) ^ sw));
      bf16x8 pa1 = *(const bf16x8*)(Pw + ((64 + 16 * g) ^ sw));
      __builtin_amdgcn_s_setprio(1);
      o5 = __builtin_amdgcn_mfma_f32_16x16x32_bf16(pa0, ones, o5, 0, 0, 0);
      o5 = __builtin_amdgcn_mfma_f32_16x16x32_bf16(pa1, ones, o5, 0, 0, 0);
#pragma unroll
      for (int nt = 0; nt < 4; ++nt) {
        int row = 16 * nt + ln;
        bf16x8 vf0 = *(const bf16x8*)(Vl + row * 64 + ((g ^ (row & 7)) << 3));
        bf16x8 vf1 = *(const bf16x8*)(Vl + row * 64 + (((4 + g) ^ (row & 7)) << 3));
        o[nt] = __builtin_amdgcn_mfma_f32_16x16x32_bf16(pa0, vf0, o[nt], 0, 0, 0);
        o[nt] = __builtin_amdgcn_mfma_f32_16x16x32_bf16(pa1, vf1, o[nt], 0, 0, 0);
      }
      __builtin_amdgcn_s_setprio(0);
    }

    if (more) __syncthreads();  // drains DMA (vmcnt0) + publishes buf^1
    cur ^= 1;
  }

  if (!split) {
    // direct write Y: lane holds O[q=4g+r][d=16nt+ln]
    const int bb = head / NH, hh = head - bb * NH;
    __bf16* Yp = Y + ((size_t)bb * S_LEN) * DMODEL + hh * HD;
#pragma unroll
    for (int r = 0; r < 4; ++r) {
      float inv = 1.0f / o5[r];
      int qr = q0 + 4 * g + r;
#pragma unroll
      for (int nt = 0; nt < 4; ++nt)
        Yp[(size_t)qr * DMODEL + 16 * nt + ln] = (__bf16)(o[nt][r] * inv);
    }
  } else {
    // partial slab: O bf16 [256 rows][64 d] + rowsum f32 [256]
    // per-head slab offsets: c4..7(np2)->0..7, c8..11(np3)->8..19, c12..15(np4)->20..35
    int soff;
    if (c < 8) soff = (c - 4) * 2 + part;
    else if (c < 12) soff = 8 + (c - 8) * 3 + part;
    else soff = 20 + (c - 12) * 4 + part;
    char* slab = Po + ((size_t)head * 36 + soff) * SLAB_STRIDE;
#pragma unroll
    for (int r = 0; r < 4; ++r) {
      int rowL = 16 * wv + 4 * g + r;
#pragma unroll
      for (int nt = 0; nt < 4; ++nt)
        *(__bf16*)(slab + (rowL * 64 + 16 * nt + ln) * 2) = (__bf16)o[nt][r];
      if (ln == 0) *(float*)(slab + 32768 + rowL * 4) = o5[r];
    }
  }
}

// ---------------- combine split-chunk partials (sum np slabs; 32 rows/block) ----------------
__global__ __launch_bounds__(256) void attn_combine(const char* __restrict__ Po,
                                                    __bf16* __restrict__ Y) {
  const int blk = blockIdx.x;  // 0..2303 = head*96 + (chunk-4)*8 + eighth
  const int head = blk / 96, rem = blk - head * 96;
  const int cc = rem >> 3, eighth = rem & 7;
  const int c = cc + 4;
  int np, boff;
  if (c < 8) {
    np = 2;
    boff = (c - 4) * 2;
  } else if (c < 12) {
    np = 3;
    boff = 8 + (c - 8) * 3;
  } else {
    np = 4;
    boff = 20 + (c - 12) * 4;
  }
  const char* s = Po + ((size_t)head * 36 + boff) * SLAB_STRIDE;
  const int tid = threadIdx.x;
  const int row = eighth * 32 + (tid >> 3), d0 = (tid & 7) * 8;

  float acc[8] = {0.f, 0.f, 0.f, 0.f, 0.f, 0.f, 0.f, 0.f};
  float rs = 0.f;
  for (int p = 0; p < np; ++p) {
    bf16x8 a = *(const bf16x8*)(s + (size_t)p * SLAB_STRIDE + (row * 64 + d0) * 2);
#pragma unroll
    for (int j = 0; j < 8; ++j) acc[j] += (float)a[j];
    rs += *(const float*)(s + (size_t)p * SLAB_STRIDE + 32768 + row * 4);
  }
  float inv = 1.0f / rs;

  const int bb = head / NH, hh = head - bb * NH;
  __bf16* yp = Y + ((size_t)bb * S_LEN + 256 * c + row) * DMODEL + hh * HD + d0;
  bf16x8 o;
#pragma unroll
  for (int j = 0; j < 8; ++j) o[j] = (__bf16)(acc[j] * inv);
  *(bf16x8*)yp = o;
}

extern "C" void kernel_launch(void* const* d_in, const int* in_sizes, int n_in,
                              void* d_out, int out_size, void* d_ws, size_t ws_size,
                              hipStream_t stream) {
  const float* x = (const float*)d_in[0];
  const float* Wqkv = (const float*)d_in[1];
  const float* bqkv = (const float*)d_in[2];
  const float* Wout = (const float*)d_in[3];
  const float* bout = (const float*)d_in[4];
  float* out = (float*)d_out;

  char* ws = (char*)d_ws;
  size_t off = 0;
  auto take = [&](size_t bytes) {
    char* p = ws + off;
    off += bytes;
    return p;
  };
  const size_t MD2 = (size_t)MTOT * DMODEL * 2;
  __bf16* xb = (__bf16*)take(MD2);
  __bf16* Wqkv_t = (__bf16*)take((size_t)3 * DMODEL * DMODEL * 2);
  __bf16* Wout_t = (__bf16*)take((size_t)DMODEL * DMODEL * 2);
  __bf16* Qb = (__bf16*)take(MD2);
  __bf16* Kb = (__bf16*)take(MD2);
  __bf16* Vtb = (__bf16*)take(MD2);
  __bf16* Yb = (__bf16*)take(MD2);
  char* Po = take((size_t)24 * 36 * SLAB_STRIDE);  // 24 heads x 36 slabs

  prep_all<<<3648, 256, 0, stream>>>(x, Wqkv, Wout, xb, Wqkv_t, Wout_t);
  gemm_qkv<<<64 * (3 * DMODEL / 128), 256, 0, stream>>>(xb, Wqkv_t, bqkv, Qb, Kb, Vtb);
  attn_fwd22<<<960, 1024, 0, stream>>>(Qb, Kb, Vtb, Yb, Po);
  attn_combine<<<2304, 256, 0, stream>>>(Po, Yb);
  gemm_out<<<64 * (DMODEL / 128), 256, 0, stream>>>(Yb, Wout_t, bout, out);
}

// Round 23
// 168.272 us; speedup vs baseline: 1.0855x; 1.0855x over previous
//
#include <hip/hip_runtime.h>

#define S_LEN 4096
#define NH 12
#define HD 64
#define DMODEL 768
#define BATCH 2
#define MTOT (BATCH * S_LEN) /* 8192 */

typedef __bf16 bf16x8 __attribute__((ext_vector_type(8)));
typedef __bf16 bf16x4 __attribute__((ext_vector_type(4)));
typedef float f32x4 __attribute__((ext_vector_type(4)));
typedef float f32x8 __attribute__((ext_vector_type(8)));

#define SM_SCALE_LOG2E 0.18033688f /* 0.125 * log2(e), folded into Q at GEMM1 */
#define SLAB_STRIDE 16896          /* 128x64 bf16 O (16384) + 128 f32 rowsum (512) */

__device__ __forceinline__ f32x4 f32x4_zero() {
  f32x4 z = {0.f, 0.f, 0.f, 0.f};
  return z;
}

// async global->LDS DMA, 16B per lane. LDS dest = wave-uniform base + lane*16
// (linear); swizzled layouts realized by pre-swizzling the per-lane GLOBAL
// source address (rule #21). Drained by the vmcnt(0) before s_barrier.
__device__ __forceinline__ void async16(const __bf16* g, void* l) {
  __builtin_amdgcn_global_load_lds(
      (const __attribute__((address_space(1))) void*)g,
      (__attribute__((address_space(3))) void*)l, 16, 0, 0);
}

// ---------------- merged prep: cvt x->bf16 + transpose both weights ----------------
// blocks 0..3071: cvt (256 f32x8 per block); 3072..3503: Wqkv^T; 3504..3647: Wout^T
__global__ __launch_bounds__(256) void prep_all(const float* __restrict__ x,
                                                const float* __restrict__ Wqkv,
                                                const float* __restrict__ Wout,
                                                __bf16* __restrict__ xb,
                                                __bf16* __restrict__ Wqkv_t,
                                                __bf16* __restrict__ Wout_t) {
  __shared__ __bf16 t[64][72];  // padded (transpose path only)
  const int bid = blockIdx.x;
  if (bid < 3072) {
    int i = bid * 256 + threadIdx.x;
    f32x8 a = ((const f32x8*)x)[i];
    bf16x8 o;
#pragma unroll
    for (int j = 0; j < 8; ++j) o[j] = (__bf16)a[j];
    ((bf16x8*)xb)[i] = o;
    return;
  }
  const float* in;
  __bf16* out;
  int N, v;
  if (bid < 3504) {
    in = Wqkv;
    out = Wqkv_t;
    N = 3 * DMODEL;
    v = bid - 3072;  // 0..431 = 12 kb x 36 nb
  } else {
    in = Wout;
    out = Wout_t;
    N = DMODEL;
    v = bid - 3504;  // 0..143 = 12 kb x 12 nb
  }
  int kb = (v % 12) * 64, nb = (v / 12) * 64;
  int c = threadIdx.x & 63, r0 = threadIdx.x >> 6;
#pragma unroll
  for (int i = 0; i < 16; ++i) {
    int r = r0 * 16 + i;
    t[c][r] = (__bf16)in[(size_t)(kb + r) * N + nb + c];
  }
  __syncthreads();
#pragma unroll
  for (int i = 0; i < 16; ++i) {
    int r = r0 * 16 + i;
    out[(size_t)(nb + r) * DMODEL + kb + c] = t[r][c];
  }
}

// ---------------- shared GEMM core: C[128x128] += A[128xK] * Bt[128xK]^T ----------------
__device__ __forceinline__ void gemm128_bt(const __bf16* __restrict__ A,
                                           const __bf16* __restrict__ Bt,
                                           int m0, int n0, int K,
                                           __bf16* Alds, __bf16* Blds,
                                           f32x4 acc[4][4]) {
  const int tid = threadIdx.x;
  const int l = tid & 63, w = tid >> 6;
  const int wr = w >> 1, wc = w & 1;
  const int g = l >> 4, ln = l & 15;

  const int rr = tid >> 3;
  const int sx = (tid & 7) ^ (rr & 7);
  const __bf16* As = A + (size_t)(m0 + rr) * K + sx * 8;
  const __bf16* Bs = Bt + (size_t)(n0 + rr) * K + sx * 8;
  char* Ad = (char*)Alds + (w << 10);
  char* Bd = (char*)Blds + (w << 10);

  for (int k0 = 0; k0 < K; k0 += 64) {
#pragma unroll
    for (int i = 0; i < 4; ++i) {
      async16(As + (size_t)(i * 32) * K + k0, Ad + i * 4096);
      async16(Bs + (size_t)(i * 32) * K + k0, Bd + i * 4096);
    }
    __syncthreads();
#pragma unroll
    for (int kk = 0; kk < 2; ++kk) {
      bf16x8 af[4], bfr[4];
#pragma unroll
      for (int mi = 0; mi < 4; ++mi) {
        int row = wr * 64 + mi * 16 + ln;
        af[mi] = *(const bf16x8*)(Alds + row * 64 + ((((kk << 2) + g) ^ (row & 7)) << 3));
      }
#pragma unroll
      for (int ni = 0; ni < 4; ++ni) {
        int row = wc * 64 + ni * 16 + ln;
        bfr[ni] = *(const bf16x8*)(Blds + row * 64 + ((((kk << 2) + g) ^ (row & 7)) << 3));
      }
#pragma unroll
      for (int mi = 0; mi < 4; ++mi)
#pragma unroll
        for (int ni = 0; ni < 4; ++ni)
          acc[mi][ni] =
              __builtin_amdgcn_mfma_f32_16x16x32_bf16(af[mi], bfr[ni], acc[mi][ni], 0, 0, 0);
    }
    __syncthreads();
  }
}

// ---------------- GEMM1: qkv = xb @ Wqkv + bqkv; Q pre-scaled by 0.125*log2e;
// scatter Q,K [B,H,S,Hd]; V transposed [B,H,Hd,S] ----------------
__global__ __launch_bounds__(256) void gemm_qkv(const __bf16* __restrict__ xb,
                                                const __bf16* __restrict__ Wt,
                                                const float* __restrict__ bqkv,
                                                __bf16* __restrict__ Qo,
                                                __bf16* __restrict__ Ko,
                                                __bf16* __restrict__ Vto) {
  __shared__ __bf16 Alds[128 * 64];
  __shared__ __bf16 Blds[128 * 64];
  int bm = blockIdx.x & 63, bn = blockIdx.x >> 6;
  int m0 = bm * 128, n0 = bn * 128;
  f32x4 acc[4][4];
#pragma unroll
  for (int i = 0; i < 4; ++i)
#pragma unroll
    for (int j = 0; j < 4; ++j) acc[i][j] = f32x4_zero();
  gemm128_bt(xb, Wt, m0, n0, DMODEL, Alds, Blds, acc);

  const int l = threadIdx.x & 63, w = threadIdx.x >> 6;
  const int wr = w >> 1, wc = w & 1, g = l >> 4, ln = l & 15;
#pragma unroll
  for (int ni = 0; ni < 4; ++ni) {
    int ncol = n0 + wc * 64 + ni * 16 + ln;
    int which = ncol / DMODEL;  // 0=q 1=k 2=v (uniform per 16-col fragment)
    int dd = ncol - which * DMODEL;
    int h = dd >> 6, hd = dd & 63;
    float bias = bqkv[ncol];
    if (which == 2) {
#pragma unroll
      for (int mi = 0; mi < 4; ++mi)
#pragma unroll
        for (int r = 0; r < 4; ++r) {
          int mrow = m0 + wr * 64 + mi * 16 + 4 * g + r;
          int b = mrow >> 12, s = mrow & (S_LEN - 1);
          float v = acc[mi][ni][r] + bias;
          Vto[(((size_t)(b * NH + h) * HD) + hd) * S_LEN + s] = (__bf16)v;
        }
    } else {
      __bf16* op = (which == 0) ? Qo : Ko;
      const float scl = (which == 0) ? SM_SCALE_LOG2E : 1.0f;
#pragma unroll
      for (int mi = 0; mi < 4; ++mi)
#pragma unroll
        for (int r = 0; r < 4; ++r) {
          int mrow = m0 + wr * 64 + mi * 16 + 4 * g + r;
          int b = mrow >> 12, s = mrow & (S_LEN - 1);
          float v = (acc[mi][ni][r] + bias) * scl;
          op[((((size_t)b * NH + h) * S_LEN) + s) * HD + hd] = (__bf16)v;
        }
    }
  }
}

// ---------------- GEMM2: out = Yb @ Wout + bout (fp32 out) ----------------
__global__ __launch_bounds__(256) void gemm_out(const __bf16* __restrict__ yb,
                                                const __bf16* __restrict__ Wt,
                                                const float* __restrict__ bout,
                                                float* __restrict__ out) {
  __shared__ __bf16 Alds[128 * 64];
  __shared__ __bf16 Blds[128 * 64];
  int bm = blockIdx.x & 63, bn = blockIdx.x >> 6;
  int m0 = bm * 128, n0 = bn * 128;
  f32x4 acc[4][4];
#pragma unroll
  for (int i = 0; i < 4; ++i)
#pragma unroll
    for (int j = 0; j < 4; ++j) acc[i][j] = f32x4_zero();
  gemm128_bt(yb, Wt, m0, n0, DMODEL, Alds, Blds, acc);

  const int l = threadIdx.x & 63, w = threadIdx.x >> 6;
  const int wr = w >> 1, wc = w & 1, g = l >> 4, ln = l & 15;
#pragma unroll
  for (int ni = 0; ni < 4; ++ni) {
    int ncol = n0 + wc * 64 + ni * 16 + ln;
    float bias = bout[ncol];
#pragma unroll
    for (int mi = 0; mi < 4; ++mi)
#pragma unroll
      for (int r = 0; r < 4; ++r) {
        int mrow = m0 + wr * 64 + mi * 16 + 4 * g + r;
        out[(size_t)mrow * DMODEL + ncol] = acc[mi][ni][r] + bias;
      }
  }
}

// ---------------- causal flash attention v18 (session best, verbatim) ----------------
// 512-thread blocks = 8 waves share ONE K/V double-buffer (LDS 48KB incl. 16KB
// P-bounce) -> 3 blocks/CU x 8 waves = 24 waves/CU. Chunk = 128 q-rows; unit =
// (head, chunk, kv-part), np = 4/3/2/1 by chunk length, 1920 units <=16 iters,
// heavy-first, XCD head affinity; exact partial slabs + combine.
__global__ __launch_bounds__(512) void attn_fwd18(const __bf16* __restrict__ Q,
                                                  const __bf16* __restrict__ K,
                                                  const __bf16* __restrict__ Vt,
                                                  __bf16* __restrict__ Y,
                                                  char* __restrict__ Po) {
  __shared__ __bf16 KVl[2][2][4096];  // [buf][K/V][8KB]: K [64kv][64d], V [64d][64kv]
  __shared__ char Plb[8][2048];       // per-wave P bounce [16 q][64 kv] pitch 128 + XOR

  const int tid = threadIdx.x;
  const int wv = tid >> 6, l = tid & 63;
  const int g = l >> 4, ln = l & 15;
  const int bi = blockIdx.x;
  const int xcd = bi & 7, j = bi >> 3;  // j in 0..239
  const int head = xcd * 3 + (j % 3);   // 3 heads per XCD
  const int r_ = j / 3;                 // rank 0..79, heavy-first

  int c, part, np;
  bool split;
  if (r_ < 32) {  // c=31..24, np=4
    c = 31 - (r_ >> 2);
    part = r_ & 3;
    np = 4;
    split = true;
  } else if (r_ < 56) {  // c=23..16, np=3
    int q = r_ - 32;
    c = 23 - q / 3;
    part = q % 3;
    np = 3;
    split = true;
  } else if (r_ < 72) {  // c=15..8, np=2
    int q = r_ - 56;
    c = 15 - (q >> 1);
    part = q & 1;
    np = 2;
    split = true;
  } else {  // c=7..0, direct
    c = 79 - r_;
    part = 0;
    np = 1;
    split = false;
  }
  const int T = 2 * c + 2;
  const int base = T / np, rem = T % np;
  const int t0 = part * base + (part < rem ? part : rem);
  const int t1 = t0 + base + (part < rem ? 1 : 0);

  const int q0 = 128 * c + 16 * wv;  // wave's first q row (global)

  const size_t hb = (size_t)head * (S_LEN * HD);
  const __bf16* Qh = Q + hb;
  const __bf16* Kh = K + hb;
  const __bf16* Vh = Vt + hb;  // [HD][S]

  const int sw = (ln & 7) << 4;
  char* Pw = Plb[wv] + ln * 128;

  // staging: 512 threads cover the 8KB tile in one shot.
  const int r0 = tid >> 3;
  const int s0 = (tid & 7) ^ (r0 & 7);
  const size_t kL = (size_t)r0 * HD + s0 * 8;
  const size_t vL = (size_t)r0 * S_LEN + s0 * 8;
  const int ldsoff = wv << 10;

  bf16x8 qf[2];
#pragma unroll
  for (int t = 0; t < 2; ++t)
    qf[t] = *(const bf16x8*)(Qh + (size_t)(q0 + ln) * HD + 32 * t + 8 * g);

  bf16x8 ones;
#pragma unroll
  for (int t = 0; t < 8; ++t) ones[t] = (__bf16)1.0f;

  f32x4 o[4], o5;
#pragma unroll
  for (int nt = 0; nt < 4; ++nt) o[nt] = f32x4_zero();
  o5 = f32x4_zero();

  // prologue: stage tile t0 into buf 0
  const __bf16* kq = Kh + (size_t)t0 * 64 * HD;
  const __bf16* vq = Vh + t0 * 64;
  {
    async16(kq + kL, (char*)&KVl[0][0][0] + ldsoff);
    async16(vq + vL, (char*)&KVl[0][1][0] + ldsoff);
    __syncthreads();
  }
  kq += (size_t)64 * HD;
  vq += 64;

  int cur = 0;
  for (int i = t0; i < t1; ++i) {
    const bool more = (i + 1) < t1;
    if (more) {  // DMA next tile into buf^1 (drained by end-of-iter barrier)
      async16(kq + kL, (char*)&KVl[cur ^ 1][0][0] + ldsoff);
      async16(vq + vL, (char*)&KVl[cur ^ 1][1][0] + ldsoff);
      kq += (size_t)64 * HD;
      vq += 64;
    }

    const __bf16* Kl = &KVl[cur][0][0];
    const __bf16* Vl = &KVl[cur][1][0];
    const int rel = q0 - 64 * i;  // >=63 full; <=-16 fully masked; else partial

    if (rel > -16) {
      // ---- QK^T + fused softmax -> P bounce ----
      if (rel >= 63) {
#pragma unroll
        for (int jt = 0; jt < 4; ++jt) {
          int row = 16 * jt + ln;
          bf16x8 kf0 = *(const bf16x8*)(Kl + row * 64 + ((g ^ (row & 7)) << 3));
          bf16x8 kf1 = *(const bf16x8*)(Kl + row * 64 + (((4 + g) ^ (row & 7)) << 3));
          f32x4 z = f32x4_zero();
          z = __builtin_amdgcn_mfma_f32_16x16x32_bf16(kf0, qf[0], z, 0, 0, 0);
          z = __builtin_amdgcn_mfma_f32_16x16x32_bf16(kf1, qf[1], z, 0, 0, 0);
          bf16x4 qd;
#pragma unroll
          for (int r = 0; r < 4; ++r) qd[r] = (__bf16)__builtin_exp2f(z[r]);
          *(bf16x4*)(Pw + ((32 * jt + 8 * g) ^ sw)) = qd;
        }
      } else {
        const int thr = rel + ln;
#pragma unroll
        for (int jt = 0; jt < 4; ++jt) {
          int row = 16 * jt + ln;
          bf16x8 kf0 = *(const bf16x8*)(Kl + row * 64 + ((g ^ (row & 7)) << 3));
          bf16x8 kf1 = *(const bf16x8*)(Kl + row * 64 + (((4 + g) ^ (row & 7)) << 3));
          f32x4 z = f32x4_zero();
          z = __builtin_amdgcn_mfma_f32_16x16x32_bf16(kf0, qf[0], z, 0, 0, 0);
          z = __builtin_amdgcn_mfma_f32_16x16x32_bf16(kf1, qf[1], z, 0, 0, 0);
          bf16x4 qd;
#pragma unroll
          for (int r = 0; r < 4; ++r) {
            float pv = __builtin_exp2f(z[r]);
            if (16 * jt + 4 * g + r > thr) pv = 0.f;
            qd[r] = (__bf16)pv;
          }
          *(bf16x4*)(Pw + ((32 * jt + 8 * g) ^ sw)) = qd;
        }
      }

      // ---- PV + ones row-sum ----
      bf16x8 pa0 = *(const bf16x8*)(Pw + ((16 * g) ^ sw));
      bf16x8 pa1 = *(const bf16x8*)(Pw + ((64 + 16 * g) ^ sw));
      __builtin_amdgcn_s_setprio(1);
      o5 = __builtin_amdgcn_mfma_f32_16x16x32_bf16(pa0, ones, o5, 0, 0, 0);
      o5 = __builtin_amdgcn_mfma_f32_16x16x32_bf16(pa1, ones, o5, 0, 0, 0);
#pragma unroll
      for (int nt = 0; nt < 4; ++nt) {
        int row = 16 * nt + ln;
        bf16x8 vf0 = *(const bf16x8*)(Vl + row * 64 + ((g ^ (row & 7)) << 3));
        bf16x8 vf1 = *(const bf16x8*)(Vl + row * 64 + (((4 + g) ^ (row & 7)) << 3));
        o[nt] = __builtin_amdgcn_mfma_f32_16x16x32_bf16(pa0, vf0, o[nt], 0, 0, 0);
        o[nt] = __builtin_amdgcn_mfma_f32_16x16x32_bf16(pa1, vf1, o[nt], 0, 0, 0);
      }
      __builtin_amdgcn_s_setprio(0);
    }

    if (more) __syncthreads();  // drains DMA (vmcnt0) + publishes buf^1
    cur ^= 1;
  }

  if (!split) {
    // direct write Y: lane holds O[q=4g+r][d=16nt+ln]
    const int bb = head / NH, hh = head - bb * NH;
    __bf16* Yp = Y + ((size_t)bb * S_LEN) * DMODEL + hh * HD;
#pragma unroll
    for (int r = 0; r < 4; ++r) {
      float inv = 1.0f / o5[r];
      int qr = q0 + 4 * g + r;
#pragma unroll
      for (int nt = 0; nt < 4; ++nt)
        Yp[(size_t)qr * DMODEL + 16 * nt + ln] = (__bf16)(o[nt][r] * inv);
    }
  } else {
    // partial slab: O bf16 [128 rows][64 d] + rowsum f32 [128]
    int soff;
    if (c < 16) soff = (c - 8) * 2 + part;
    else if (c < 24) soff = 16 + (c - 16) * 3 + part;
    else soff = 40 + (c - 24) * 4 + part;
    char* slab = Po + ((size_t)head * 72 + soff) * SLAB_STRIDE;
#pragma unroll
    for (int r = 0; r < 4; ++r) {
      int rowL = 16 * wv + 4 * g + r;
#pragma unroll
      for (int nt = 0; nt < 4; ++nt)
        *(__bf16*)(slab + (rowL * 64 + 16 * nt + ln) * 2) = (__bf16)o[nt][r];
      if (ln == 0) *(float*)(slab + 16384 + rowL * 4) = o5[r];
    }
  }
}

// ---------------- combine split-chunk partials (sum np slabs; 32 rows/block) ----------------
__global__ __launch_bounds__(256) void attn_combine(const char* __restrict__ Po,
                                                    __bf16* __restrict__ Y) {
  const int blk = blockIdx.x;  // 0..2303 = head * 96 + (chunk-8)*4 + quarter
  const int head = blk / 96, rem = blk - head * 96;
  const int cc = rem >> 2, quarter = rem & 3;
  const int c = cc + 8;
  int np, boff;
  if (c < 16) {
    np = 2;
    boff = (c - 8) * 2;
  } else if (c < 24) {
    np = 3;
    boff = 16 + (c - 16) * 3;
  } else {
    np = 4;
    boff = 40 + (c - 24) * 4;
  }
  const char* s = Po + ((size_t)head * 72 + boff) * SLAB_STRIDE;
  const int tid = threadIdx.x;
  const int row = quarter * 32 + (tid >> 3), d0 = (tid & 7) * 8;

  float acc[8] = {0.f, 0.f, 0.f, 0.f, 0.f, 0.f, 0.f, 0.f};
  float rs = 0.f;
  for (int p = 0; p < np; ++p) {
    bf16x8 a = *(const bf16x8*)(s + (size_t)p * SLAB_STRIDE + (row * 64 + d0) * 2);
#pragma unroll
    for (int j = 0; j < 8; ++j) acc[j] += (float)a[j];
    rs += *(const float*)(s + (size_t)p * SLAB_STRIDE + 16384 + row * 4);
  }
  float inv = 1.0f / rs;

  const int bb = head / NH, hh = head - bb * NH;
  __bf16* yp = Y + ((size_t)bb * S_LEN + 128 * c + row) * DMODEL + hh * HD + d0;
  bf16x8 o;
#pragma unroll
  for (int j = 0; j < 8; ++j) o[j] = (__bf16)(acc[j] * inv);
  *(bf16x8*)yp = o;
}

extern "C" void kernel_launch(void* const* d_in, const int* in_sizes, int n_in,
                              void* d_out, int out_size, void* d_ws, size_t ws_size,
                              hipStream_t stream) {
  const float* x = (const float*)d_in[0];
  const float* Wqkv = (const float*)d_in[1];
  const float* bqkv = (const float*)d_in[2];
  const float* Wout = (const float*)d_in[3];
  const float* bout = (const float*)d_in[4];
  float* out = (float*)d_out;

  char* ws = (char*)d_ws;
  size_t off = 0;
  auto take = [&](size_t bytes) {
    char* p = ws + off;
    off += bytes;
    return p;
  };
  const size_t MD2 = (size_t)MTOT * DMODEL * 2;
  __bf16* xb = (__bf16*)take(MD2);
  __bf16* Wqkv_t = (__bf16*)take((size_t)3 * DMODEL * DMODEL * 2);
  __bf16* Wout_t = (__bf16*)take((size_t)DMODEL * DMODEL * 2);
  __bf16* Qb = (__bf16*)take(MD2);
  __bf16* Kb = (__bf16*)take(MD2);
  __bf16* Vtb = (__bf16*)take(MD2);
  __bf16* Yb = (__bf16*)take(MD2);
  char* Po = take((size_t)24 * 72 * SLAB_STRIDE);  // 24 heads x 72 slabs

  prep_all<<<3648, 256, 0, stream>>>(x, Wqkv, Wout, xb, Wqkv_t, Wout_t);
  gemm_qkv<<<64 * (3 * DMODEL / 128), 256, 0, stream>>>(xb, Wqkv_t, bqkv, Qb, Kb, Vtb);
  attn_fwd18<<<1920, 512, 0, stream>>>(Qb, Kb, Vtb, Yb, Po);
  attn_combine<<<2304, 256, 0, stream>>>(Po, Yb);
  gemm_out<<<64 * (DMODEL / 128), 256, 0, stream>>>(Yb, Wout_t, bout, out);
}